// Round 1
// baseline (217.426 us; speedup 1.0000x reference)
//
#include <hip/hip_runtime.h>

// PoseEncoding: out[b,s,n,c] = x[b,s,n,c] + pe[n,c]
//   pe[n, 2k]   = sin(n / (2000*k/256 + 0.01))
//   pe[n, 2k+1] = cos(n / (2000*k/256 + 0.01))
// Shapes: B=8, S=16, N=1024, d=256 (all fp32). Memory-bound streaming add.
//
// One thread per float4 (4 consecutive channels = 2 (sin,cos) pairs).
// Flat float4 index i: c4 = i % 64 (d/4=64), n = (i/64) % 1024.
// denom for pair k: 7.8125*k + 0.01  (1000/128 = 7.8125, exact in binary;
// matches reference fp32 arithmetic).

#define N4_TOTAL (8 * 16 * 1024 * 256 / 4)

__global__ __launch_bounds__(256) void pose_add_kernel(
    const float4* __restrict__ x, float4* __restrict__ out) {
    int i = blockIdx.x * blockDim.x + threadIdx.x;
    if (i >= N4_TOTAL) return;

    int c4 = i & 63;           // which float4 within the d=256 row
    int n  = (i >> 6) & 1023;  // position within N=1024
    float fn = (float)n;

    int   k0     = c4 << 1;          // even pair index
    float denom0 = 7.8125f * (float)k0 + 0.01f;
    float denom1 = 7.8125f * (float)(k0 + 1) + 0.01f;
    float a0 = fn / denom0;
    float a1 = fn / denom1;

    float4 v = x[i];
    float4 r;
    r.x = v.x + __sinf(a0);
    r.y = v.y + __cosf(a0);
    r.z = v.z + __sinf(a1);
    r.w = v.w + __cosf(a1);
    out[i] = r;
}

extern "C" void kernel_launch(void* const* d_in, const int* in_sizes, int n_in,
                              void* d_out, int out_size, void* d_ws, size_t ws_size,
                              hipStream_t stream) {
    const float4* x   = (const float4*)d_in[0];
    float4*       out = (float4*)d_out;
    int blocks = (N4_TOTAL + 255) / 256;  // 32768
    pose_add_kernel<<<blocks, 256, 0, stream>>>(x, out);
}